// Round 1
// baseline (269.907 us; speedup 1.0000x reference)
//
#include <hip/hip_runtime.h>

typedef _Float16 half8 __attribute__((ext_vector_type(8)));
typedef _Float16 half4 __attribute__((ext_vector_type(4)));
typedef float floatx16 __attribute__((ext_vector_type(16)));

#define MFMA_F16(A, B, C) __builtin_amdgcn_mfma_f32_32x32x16_f16(A, B, C, 0, 0, 0)

constexpr int Bn = 4;     // batch
constexpr int Cc = 256;   // channels
constexpr int Cq = 32;    // C/8
constexpr int Nn = 4096;  // tokens (64*64)

__device__ inline floatx16 zero16() {
  floatx16 z;
#pragma unroll
  for (int i = 0; i < 16; ++i) z[i] = 0.f;
  return z;
}

__device__ inline half8 cvt8(float4 a, float4 b) {
  half8 r;
  r[0] = (_Float16)a.x; r[1] = (_Float16)a.y; r[2] = (_Float16)a.z; r[3] = (_Float16)a.w;
  r[4] = (_Float16)b.x; r[5] = (_Float16)b.y; r[6] = (_Float16)b.z; r[7] = (_Float16)b.w;
  return r;
}

// ---------------------------------------------------------------------------
// Kernel 0: x[b][c][n] fp32 -> xT[b][n][c] f16  (LDS transpose, 64x64 tiles)
// ---------------------------------------------------------------------------
__global__ __launch_bounds__(256) void k_xt(const float* __restrict__ x,
                                            _Float16* __restrict__ xT) {
  __shared__ _Float16 t[64 * 66];
  int blk = blockIdx.x;
  int b = blk >> 8;          // 256 tiles per batch
  int rem = blk & 255;
  int ct = rem & 3, nt = rem >> 2;
  int c0 = ct * 64, n0 = nt * 64;
  int tid = threadIdx.x;
  int col = tid & 63, row4 = tid >> 6;
  const float* xp = x + ((size_t)b * Cc + c0) * Nn + n0;
#pragma unroll
  for (int it = 0; it < 16; ++it) {
    int cl = it * 4 + row4;
    t[cl * 66 + col] = (_Float16)xp[(size_t)cl * Nn + col];
  }
  __syncthreads();
  _Float16* op = xT + ((size_t)b * Nn + n0) * Cc + c0;
#pragma unroll
  for (int it = 0; it < 16; ++it) {
    int nl = it * 4 + row4;
    op[(size_t)nl * Cc + col] = t[col * 66 + nl];
  }
}

// ---------------------------------------------------------------------------
// Kernel 1: projections.
//  Q[b][n][o] = sum_c xT[n][c]*Wf[o][c] + bf[o]   (f16, token-major)
//  K likewise with Wg/bg.
//  Vt[b][c][n] = sum_ci Wh[c][ci]*xT[n][ci] + bh[c] (f16, channel-major)
// One wave = one 32x32 output tile over full K=256 contraction.
// Jobs: [0,512) Q, [512,1024) K, [1024,5120) V.  4 waves/block -> 1280 blocks.
// ---------------------------------------------------------------------------
__global__ __launch_bounds__(256) void k_proj(
    const _Float16* __restrict__ xT,
    const float* __restrict__ Wf, const float* __restrict__ bf,
    const float* __restrict__ Wg, const float* __restrict__ bg,
    const float* __restrict__ Wh, const float* __restrict__ bh,
    _Float16* __restrict__ Q, _Float16* __restrict__ K,
    _Float16* __restrict__ Vt) {
  int tid = threadIdx.x;
  int wave = tid >> 6, lane = tid & 63;
  int ml = lane & 31, h = lane >> 5;
  int jid = blockIdx.x * 4 + wave;
  floatx16 acc = zero16();

  if (jid < 1024) {
    // ---- Q or K: D[n][o] = A(xT[n][c]) * B(W^T[c][o]) ----
    const float* W = (jid < 512) ? Wf : Wg;
    const float* bias = (jid < 512) ? bf : bg;
    _Float16* dst = (jid < 512) ? Q : K;
    int j2 = jid & 511;
    int b = j2 >> 7, nt = j2 & 127;
    int n0 = nt * 32;
    const _Float16* ap = xT + ((size_t)b * Nn + n0 + ml) * Cc + h * 8;
    const float* wp = W + (size_t)ml * Cc + h * 8;
#pragma unroll
    for (int kc = 0; kc < 16; ++kc) {
      half8 a = *(const half8*)(ap + kc * 16);
      float4 w0 = *(const float4*)(wp + kc * 16);
      float4 w1 = *(const float4*)(wp + kc * 16 + 4);
      acc = MFMA_F16(a, cvt8(w0, w1), acc);
    }
    float bv = bias[ml];
    _Float16* op = dst + ((size_t)b * Nn + n0) * Cq + ml;
#pragma unroll
    for (int r = 0; r < 16; ++r) {
      int row = (r & 3) + 8 * (r >> 2) + 4 * h;
      op[(size_t)row * Cq] = (_Float16)(acc[r] + bv);
    }
  } else {
    // ---- V: D[c][n] = A(Wh[c][ci]) * B(xT[n][ci]) ----
    int v = jid - 1024;
    int b = v >> 10, r2 = v & 1023;
    int ct = r2 >> 7, nt = r2 & 127;
    int c0 = ct * 32, n0 = nt * 32;
    const float* wp = Wh + (size_t)(c0 + ml) * Cc + h * 8;
    const _Float16* bp = xT + ((size_t)b * Nn + n0 + ml) * Cc + h * 8;
#pragma unroll
    for (int kc = 0; kc < 16; ++kc) {
      float4 w0 = *(const float4*)(wp + kc * 16);
      float4 w1 = *(const float4*)(wp + kc * 16 + 4);
      half8 bfrag = *(const half8*)(bp + kc * 16);
      acc = MFMA_F16(cvt8(w0, w1), bfrag, acc);
    }
    _Float16* op = Vt + ((size_t)b * Cc + c0) * (size_t)Nn + n0 + ml;
#pragma unroll
    for (int q = 0; q < 4; ++q) {
      float4 bq = *(const float4*)(bh + c0 + 8 * q + 4 * h);
      const float* bqp = (const float*)&bq;
#pragma unroll
      for (int i = 0; i < 4; ++i) {
        int row = 8 * q + 4 * h + i;
        op[(size_t)row * Nn] = (_Float16)(acc[4 * q + i] + bqp[i]);
      }
    }
  }
}

// ---------------------------------------------------------------------------
// Kernel 2: pass-1 row max.  M[b][m] = max_n sum_o K[n][o]*Q[m][o]
// Block = 4 waves, one 32-wide m tile; wave w covers n in [w*1024,(w+1)*1024).
// MFMA sequence is bitwise identical to pass 2 -> exp(s-M) <= 1 exactly.
// ---------------------------------------------------------------------------
__global__ __launch_bounds__(256) void k_rowmax(const _Float16* __restrict__ Q,
                                                const _Float16* __restrict__ K,
                                                float* __restrict__ M) {
  __shared__ float red[4][32];
  int tid = threadIdx.x, wave = tid >> 6, lane = tid & 63;
  int ml = lane & 31, h = lane >> 5;
  int b = blockIdx.x >> 7, mt = blockIdx.x & 127;
  int m0 = mt * 32;
  const _Float16* qp = Q + ((size_t)b * Nn + m0 + ml) * Cq + h * 8;
  half8 qb0 = *(const half8*)(qp);
  half8 qb1 = *(const half8*)(qp + 16);
  const _Float16* kp = K + ((size_t)b * Nn + wave * 1024 + ml) * Cq + h * 8;
  float mx = -3.0e38f;
  for (int t = 0; t < 32; ++t) {
    floatx16 s = zero16();
    half8 k0 = *(const half8*)(kp + (size_t)t * 32 * Cq);
    half8 k1 = *(const half8*)(kp + (size_t)t * 32 * Cq + 16);
    s = MFMA_F16(k0, qb0, s);
    s = MFMA_F16(k1, qb1, s);
#pragma unroll
    for (int i = 0; i < 16; ++i) mx = fmaxf(mx, s[i]);
  }
  mx = fmaxf(mx, __shfl_xor(mx, 32, 64));
  if (h == 0) red[wave][ml] = mx;
  __syncthreads();
  if (tid < 32) {
    float m2 = fmaxf(fmaxf(red[0][tid], red[1][tid]),
                     fmaxf(red[2][tid], red[3][tid]));
    M[(size_t)b * Nn + m0 + tid] = m2;
  }
}

// ---------------------------------------------------------------------------
// Kernel 3: pass-2 attention, transposed (S^T / O^T), no rescaling.
// Block = 512 thr = 8 waves: wave = (msub in {0,1}) x (cq in {0..3}).
// Per wave: 32 queries (cols) x 64 channels, loop n-tiles of 64.
// P^T via per-wave private LDS (no barriers). Epilogue: coalesced
// out[b][c][m] = gamma*(O/l) + input.
// ---------------------------------------------------------------------------
__global__ __launch_bounds__(512, 2) void k_attn(
    const _Float16* __restrict__ Q, const _Float16* __restrict__ K,
    const _Float16* __restrict__ Vt, const float* __restrict__ M,
    const float* __restrict__ inp, const float* __restrict__ gamma,
    float* __restrict__ out) {
  __shared__ _Float16 pl[8][32 * 72];  // per-wave P^T tile [m=32][n=64] stride 72
  int tid = threadIdx.x, wave = tid >> 6, lane = tid & 63;
  int ml = lane & 31, h = lane >> 5;
  int msub = wave & 1, cq = wave >> 1;
  int b = blockIdx.x >> 6, mt = blockIdx.x & 63;
  int m0 = mt * 64 + msub * 32;
  int c0 = cq * 64;

  const _Float16* qp = Q + ((size_t)b * Nn + m0 + ml) * Cq + h * 8;
  half8 qb0 = *(const half8*)(qp);
  half8 qb1 = *(const half8*)(qp + 16);
  float Mv = M[(size_t)b * Nn + m0 + ml];

  floatx16 o0 = zero16();
  floatx16 o1 = zero16();
  floatx16 lv = zero16();
  _Float16* plw = &pl[wave][0];
  const _Float16* kbase = K + ((size_t)b * Nn + ml) * Cq + h * 8;
  const _Float16* vbase =
      Vt + ((size_t)b * Cc + c0 + ml) * (size_t)Nn + h * 8;

  for (int nt = 0; nt < 64; ++nt) {
    int n0 = nt * 64;
#pragma unroll
    for (int ns = 0; ns < 2; ++ns) {
      floatx16 s = zero16();
      const _Float16* kp = kbase + (size_t)(n0 + ns * 32) * Cq;
      half8 k0 = *(const half8*)(kp);
      half8 k1 = *(const half8*)(kp + 16);
      s = MFMA_F16(k0, qb0, s);
      s = MFMA_F16(k1, qb1, s);
#pragma unroll
      for (int q = 0; q < 4; ++q) {
        float p0 = __expf(s[4 * q + 0] - Mv);
        float p1 = __expf(s[4 * q + 1] - Mv);
        float p2 = __expf(s[4 * q + 2] - Mv);
        float p3 = __expf(s[4 * q + 3] - Mv);
        lv[4 * q + 0] += p0; lv[4 * q + 1] += p1;
        lv[4 * q + 2] += p2; lv[4 * q + 3] += p3;
        half4 pk;
        pk[0] = (_Float16)p0; pk[1] = (_Float16)p1;
        pk[2] = (_Float16)p2; pk[3] = (_Float16)p3;
        int nrow = ns * 32 + 8 * q + 4 * h;
        *(half4*)(plw + ml * 72 + nrow) = pk;  // ds_write_b64
      }
    }
    // PV^T: O^T[c][m] += V^T[c][n] * P^T[n][m]
#pragma unroll
    for (int kc = 0; kc < 4; ++kc) {
      half8 pb = *(const half8*)(plw + ml * 72 + kc * 16 + h * 8);
      half8 v0 = *(const half8*)(vbase + n0 + kc * 16);
      half8 v1 = *(const half8*)(vbase + (size_t)32 * Nn + n0 + kc * 16);
      o0 = MFMA_F16(v0, pb, o0);
      o1 = MFMA_F16(v1, pb, o1);
    }
  }

  float l = 0.f;
#pragma unroll
  for (int i = 0; i < 16; ++i) l += lv[i];
  l += __shfl_xor(l, 32, 64);
  float inv = gamma[0] / l;

  size_t obase = (size_t)b * Cc * Nn + (size_t)m0 + ml;
#pragma unroll
  for (int r = 0; r < 16; ++r) {
    int row0 = c0 + (r & 3) + 8 * (r >> 2) + 4 * h;
    size_t a0 = obase + (size_t)row0 * Nn;
    size_t a1 = obase + (size_t)(row0 + 32) * Nn;
    out[a0] = o0[r] * inv + inp[a0];
    out[a1] = o1[r] * inv + inp[a1];
  }
}

// ---------------------------------------------------------------------------
extern "C" void kernel_launch(void* const* d_in, const int* in_sizes, int n_in,
                              void* d_out, int out_size, void* d_ws,
                              size_t ws_size, hipStream_t stream) {
  const float* x = (const float*)d_in[0];
  const float* Wf = (const float*)d_in[1];
  const float* bf = (const float*)d_in[2];
  const float* Wg = (const float*)d_in[3];
  const float* bg = (const float*)d_in[4];
  const float* Wh = (const float*)d_in[5];
  const float* bh = (const float*)d_in[6];
  const float* gamma = (const float*)d_in[7];
  float* out = (float*)d_out;

  char* ws = (char*)d_ws;
  _Float16* xT = (_Float16*)(ws);                 // 8,388,608 B
  _Float16* Q  = (_Float16*)(ws + 8388608);       // 1,048,576 B
  _Float16* K  = (_Float16*)(ws + 9437184);       // 1,048,576 B
  _Float16* Vt = (_Float16*)(ws + 10485760);      // 8,388,608 B
  float*    M  = (float*)   (ws + 18874368);      //    65,536 B

  k_xt<<<dim3(1024), dim3(256), 0, stream>>>(x, xT);
  k_proj<<<dim3(1280), dim3(256), 0, stream>>>(xT, Wf, bf, Wg, bg, Wh, bh, Q, K, Vt);
  k_rowmax<<<dim3(512), dim3(256), 0, stream>>>(Q, K, M);
  k_attn<<<dim3(256), dim3(512), 0, stream>>>(Q, K, Vt, M, x, gamma, out);
}

// Round 3
// 198.573 us; speedup vs baseline: 1.3592x; 1.3592x over previous
//
#include <hip/hip_runtime.h>

typedef _Float16 half8 __attribute__((ext_vector_type(8)));
typedef _Float16 half4 __attribute__((ext_vector_type(4)));
typedef float floatx16 __attribute__((ext_vector_type(16)));

#define MFMA_F16(A, B, C) __builtin_amdgcn_mfma_f32_32x32x16_f16(A, B, C, 0, 0, 0)

constexpr int Bn = 4;     // batch
constexpr int Cc = 256;   // channels
constexpr int Cq = 32;    // C/8
constexpr int Nn = 4096;  // tokens (64*64)

__device__ inline floatx16 zero16() {
  floatx16 z;
#pragma unroll
  for (int i = 0; i < 16; ++i) z[i] = 0.f;
  return z;
}

__device__ inline half8 cvt8(float4 a, float4 b) {
  half8 r;
  r[0] = (_Float16)a.x; r[1] = (_Float16)a.y; r[2] = (_Float16)a.z; r[3] = (_Float16)a.w;
  r[4] = (_Float16)b.x; r[5] = (_Float16)b.y; r[6] = (_Float16)b.z; r[7] = (_Float16)b.w;
  return r;
}

// ---------------------------------------------------------------------------
// Kernel 0: x[b][c][n] fp32 -> xT[b][n][c] f16  (LDS transpose, 64x64 tiles)
// ---------------------------------------------------------------------------
__global__ __launch_bounds__(256) void k_xt(const float* __restrict__ x,
                                            _Float16* __restrict__ xT) {
  __shared__ _Float16 t[64 * 66];
  int blk = blockIdx.x;
  int b = blk >> 8;
  int rem = blk & 255;
  int ct = rem & 3, nt = rem >> 2;
  int c0 = ct * 64, n0 = nt * 64;
  int tid = threadIdx.x;
  int col = tid & 63, row4 = tid >> 6;
  const float* xp = x + ((size_t)b * Cc + c0) * Nn + n0;
#pragma unroll
  for (int it = 0; it < 16; ++it) {
    int cl = it * 4 + row4;
    t[cl * 66 + col] = (_Float16)xp[(size_t)cl * Nn + col];
  }
  __syncthreads();
  _Float16* op = xT + ((size_t)b * Nn + n0) * Cc + c0;
#pragma unroll
  for (int it = 0; it < 16; ++it) {
    int nl = it * 4 + row4;
    op[(size_t)nl * Cc + col] = t[col * 66 + nl];
  }
}

// ---------------------------------------------------------------------------
// Kernel 1: projections (unchanged).
// ---------------------------------------------------------------------------
__global__ __launch_bounds__(256) void k_proj(
    const _Float16* __restrict__ xT,
    const float* __restrict__ Wf, const float* __restrict__ bf,
    const float* __restrict__ Wg, const float* __restrict__ bg,
    const float* __restrict__ Wh, const float* __restrict__ bh,
    _Float16* __restrict__ Q, _Float16* __restrict__ K,
    _Float16* __restrict__ Vt) {
  int tid = threadIdx.x;
  int wave = tid >> 6, lane = tid & 63;
  int ml = lane & 31, h = lane >> 5;
  int jid = blockIdx.x * 4 + wave;
  floatx16 acc = zero16();

  if (jid < 1024) {
    const float* W = (jid < 512) ? Wf : Wg;
    const float* bias = (jid < 512) ? bf : bg;
    _Float16* dst = (jid < 512) ? Q : K;
    int j2 = jid & 511;
    int b = j2 >> 7, nt = j2 & 127;
    int n0 = nt * 32;
    const _Float16* ap = xT + ((size_t)b * Nn + n0 + ml) * Cc + h * 8;
    const float* wp = W + (size_t)ml * Cc + h * 8;
#pragma unroll
    for (int kc = 0; kc < 16; ++kc) {
      half8 a = *(const half8*)(ap + kc * 16);
      float4 w0 = *(const float4*)(wp + kc * 16);
      float4 w1 = *(const float4*)(wp + kc * 16 + 4);
      acc = MFMA_F16(a, cvt8(w0, w1), acc);
    }
    float bv = bias[ml];
    _Float16* op = dst + ((size_t)b * Nn + n0) * Cq + ml;
#pragma unroll
    for (int r = 0; r < 16; ++r) {
      int row = (r & 3) + 8 * (r >> 2) + 4 * h;
      op[(size_t)row * Cq] = (_Float16)(acc[r] + bv);
    }
  } else {
    int v = jid - 1024;
    int b = v >> 10, r2 = v & 1023;
    int ct = r2 >> 7, nt = r2 & 127;
    int c0 = ct * 32, n0 = nt * 32;
    const float* wp = Wh + (size_t)(c0 + ml) * Cc + h * 8;
    const _Float16* bp = xT + ((size_t)b * Nn + n0 + ml) * Cc + h * 8;
#pragma unroll
    for (int kc = 0; kc < 16; ++kc) {
      float4 w0 = *(const float4*)(wp + kc * 16);
      float4 w1 = *(const float4*)(wp + kc * 16 + 4);
      half8 bfrag = *(const half8*)(bp + kc * 16);
      acc = MFMA_F16(cvt8(w0, w1), bfrag, acc);
    }
    _Float16* op = Vt + ((size_t)b * Cc + c0) * (size_t)Nn + n0 + ml;
#pragma unroll
    for (int q = 0; q < 4; ++q) {
      float4 bq = *(const float4*)(bh + c0 + 8 * q + 4 * h);
      const float* bqp = (const float*)&bq;
#pragma unroll
      for (int i = 0; i < 4; ++i) {
        int row = 8 * q + 4 * h + i;
        op[(size_t)row * Nn] = (_Float16)(acc[4 * q + i] + bqp[i]);
      }
    }
  }
}

// ---------------------------------------------------------------------------
// Kernel 2: pass-1 row max, 8 waves (512 n per wave, 16 iters).
// MFMA sequence bitwise identical to k_attn's S -> exp(s-M) <= 1 exactly.
// ---------------------------------------------------------------------------
__global__ __launch_bounds__(512) void k_rowmax(const _Float16* __restrict__ Q,
                                                const _Float16* __restrict__ K,
                                                float* __restrict__ M) {
  __shared__ float red[8][32];
  int tid = threadIdx.x, w = tid >> 6, lane = tid & 63;
  int ml = lane & 31, h = lane >> 5;
  int b = blockIdx.x >> 7, mt = blockIdx.x & 127;
  int m0 = mt * 32;
  const _Float16* qp = Q + ((size_t)b * Nn + m0 + ml) * Cq + h * 8;
  half8 qb0 = *(const half8*)(qp);
  half8 qb1 = *(const half8*)(qp + 16);
  const _Float16* kp = K + ((size_t)b * Nn + w * 512 + ml) * Cq + h * 8;
  float mx = -3.0e38f;
  for (int t = 0; t < 16; ++t) {
    floatx16 s = zero16();
    half8 k0 = *(const half8*)(kp + (size_t)t * 32 * Cq);
    half8 k1 = *(const half8*)(kp + (size_t)t * 32 * Cq + 16);
    s = MFMA_F16(k0, qb0, s);
    s = MFMA_F16(k1, qb1, s);
#pragma unroll
    for (int i = 0; i < 16; ++i) mx = fmaxf(mx, s[i]);
  }
  mx = fmaxf(mx, __shfl_xor(mx, 32, 64));
  if (h == 0) red[w][ml] = mx;
  __syncthreads();
  if (tid < 32) {
    float m2 = red[0][tid];
#pragma unroll
    for (int i = 1; i < 8; ++i) m2 = fmaxf(m2, red[i][tid]);
    M[(size_t)b * Nn + m0 + tid] = m2;
  }
}

// ---------------------------------------------------------------------------
// Kernel 3: pass-2 attention v3. Shared P tile computed once per block.
// P layout: [2 bufs][64 m-rows][128 n-cols], row stride 128 (NO pad, no
// overflow: max index 16383 < 2*64*128). 16B chunk XOR swizzle:
//   chunk' = chunk ^ (row & 15)   (chunk = n>>3)
// -> PV reads are 16B-aligned ds_read_b128, conflict-free (2-way only);
//    S writes are half4 (4-way, only 4/iter).
// Grid: NC * 4 * 64 blocks of 512 thr (8 waves).
// S phase: wave w=(msub,nq) -> 32m x 32n subtile of 64m x 128n P tile.
// PV phase: wave w -> channels [w*32,(w+1)*32), both m-halves.
// Outputs unnormalized f16 O-partials + fp32 l-partials (global M makes
// chunk partials additive); k_fin combines.
// ---------------------------------------------------------------------------
__global__ __launch_bounds__(512, 4) void k_attn(
    const _Float16* __restrict__ Q, const _Float16* __restrict__ K,
    const _Float16* __restrict__ Vt, const float* __restrict__ M,
    _Float16* __restrict__ Opart, float* __restrict__ lpart, int nspan) {
  __shared__ _Float16 P[2 * 64 * 128];
  __shared__ float lred[8][32];
  int tid = threadIdx.x, w = tid >> 6, lane = tid & 63;
  int ml = lane & 31, h = lane >> 5;
  int msub = w & 1, nq = w >> 1;
  int bx = blockIdx.x;
  int mt = bx & 63, b = (bx >> 6) & 3, nc = bx >> 8;
  int m0 = mt * 64;
  int nbase0 = nc * nspan;
  int sw = ml & 15;  // XOR swizzle key (row & 15; row = {msub*32|0|32}+ml)

  // S-phase Q fragment: columns m = m0 + msub*32 + ml
  const _Float16* qp = Q + ((size_t)b * Nn + m0 + msub * 32 + ml) * Cq + h * 8;
  half8 qb0 = *(const half8*)(qp);
  half8 qb1 = *(const half8*)(qp + 16);
  float Mv = M[(size_t)b * Nn + m0 + msub * 32 + ml];
  float lacc = 0.f;

  const _Float16* kbase =
      K + ((size_t)b * Nn + nbase0 + nq * 32 + ml) * Cq + h * 8;
  int c0 = w * 32;
  const _Float16* vbase =
      Vt + ((size_t)b * Cc + c0 + ml) * (size_t)Nn + nbase0 + h * 8;

  floatx16 o0 = zero16(), o1 = zero16();
  int iters = nspan >> 7;
  int buf = 0;
  // S-phase write base: row = msub*32+ml, chunkRaw = nq*4+q, intra = 4h
  _Float16* pwbase = &P[(msub * 32 + ml) * 128];
  // PV read bases: rows ml (m-half 0) and 32+ml (m-half 1)
  const _Float16* pr0 = &P[ml * 128];
  const _Float16* pr1 = &P[(32 + ml) * 128];

  for (int it = 0; it < iters; ++it) {
    int noff = it * 128;
    // ---- S phase: one 32x32 subtile per wave ----
    {
      floatx16 s = zero16();
      const _Float16* kp = kbase + (size_t)noff * Cq;
      half8 k0 = *(const half8*)(kp);
      half8 k1 = *(const half8*)(kp + 16);
      s = MFMA_F16(k0, qb0, s);
      s = MFMA_F16(k1, qb1, s);
      _Float16* pw = pwbase + buf * (64 * 128);
#pragma unroll
      for (int q = 0; q < 4; ++q) {
        float p0 = __expf(s[4 * q + 0] - Mv);
        float p1 = __expf(s[4 * q + 1] - Mv);
        float p2 = __expf(s[4 * q + 2] - Mv);
        float p3 = __expf(s[4 * q + 3] - Mv);
        lacc += (p0 + p1) + (p2 + p3);
        half4 pk;
        pk[0] = (_Float16)p0; pk[1] = (_Float16)p1;
        pk[2] = (_Float16)p2; pk[3] = (_Float16)p3;
        int chunk = (nq * 4 + q) ^ sw;
        *(half4*)(pw + chunk * 8 + 4 * h) = pk;  // ds_write_b64
      }
    }
    __syncthreads();
    // ---- PV phase: O^T[c][m] += V^T[c][n] * P^T[n][m] ----
    {
      const _Float16* vp = vbase + noff;
      const _Float16* p0b = pr0 + buf * (64 * 128);
      const _Float16* p1b = pr1 + buf * (64 * 128);
#pragma unroll
      for (int kc = 0; kc < 8; ++kc) {
        half8 vf = *(const half8*)(vp + kc * 16);
        int chunk = (kc * 2 + h) ^ sw;
        half8 pb0 = *(const half8*)(p0b + chunk * 8);  // ds_read_b128
        half8 pb1 = *(const half8*)(p1b + chunk * 8);
        o0 = MFMA_F16(vf, pb0, o0);
        o1 = MFMA_F16(vf, pb1, o1);
      }
    }
    buf ^= 1;
  }

  // ---- l reduction: wave w holds partial l for msub=w&1, n-stripe nq ----
  lacc += __shfl_xor(lacc, 32, 64);
  if (h == 0) lred[w][ml] = lacc;
  __syncthreads();
  if (w < 2 && h == 0) {
    float lsum = lred[w][ml] + lred[w + 2][ml] + lred[w + 4][ml] + lred[w + 6][ml];
    lpart[((size_t)nc * Bn + b) * Nn + m0 + w * 32 + ml] = lsum;
  }

  // ---- store unnormalized O^T partials (f16) ----
  _Float16* op0 = Opart + ((size_t)((size_t)nc * Bn + b) * Cc) * Nn + (m0 + ml);
#pragma unroll
  for (int r = 0; r < 16; ++r) {
    int c = c0 + (r & 3) + 8 * (r >> 2) + 4 * h;
    op0[(size_t)c * Nn] = (_Float16)o0[r];
    op0[(size_t)c * Nn + 32] = (_Float16)o1[r];
  }
}

// ---------------------------------------------------------------------------
// Kernel 4: combine chunk partials: out = gamma*(sum O)/(sum l) + input
// ---------------------------------------------------------------------------
__global__ __launch_bounds__(256) void k_fin(const _Float16* __restrict__ Op,
                                             const float* __restrict__ lp,
                                             const float* __restrict__ inp,
                                             const float* __restrict__ gamma,
                                             float* __restrict__ out, int NC) {
  int i4 = (blockIdx.x * 256 + threadIdx.x) * 4;
  int m = i4 & (Nn - 1);
  int bc = i4 >> 12;        // b*256 + c
  int b = bc >> 8;
  float ax = 0.f, ay = 0.f, az = 0.f, aw = 0.f;
  float lx = 0.f, ly = 0.f, lz = 0.f, lw = 0.f;
  for (int nc = 0; nc < NC; ++nc) {
    half4 o = *(const half4*)(Op + ((size_t)nc * Bn * Cc + bc) * Nn + m);
    float4 lv = *(const float4*)(lp + ((size_t)nc * Bn + b) * Nn + m);
    ax += (float)o[0]; ay += (float)o[1]; az += (float)o[2]; aw += (float)o[3];
    lx += lv.x; ly += lv.y; lz += lv.z; lw += lv.w;
  }
  float g = gamma[0];
  float4 xi = *(const float4*)(inp + (size_t)i4);
  float4 r;
  r.x = g * ax / lx + xi.x;
  r.y = g * ay / ly + xi.y;
  r.z = g * az / lz + xi.z;
  r.w = g * aw / lw + xi.w;
  *(float4*)(out + (size_t)i4) = r;
}

// ---------------------------------------------------------------------------
extern "C" void kernel_launch(void* const* d_in, const int* in_sizes, int n_in,
                              void* d_out, int out_size, void* d_ws,
                              size_t ws_size, hipStream_t stream) {
  const float* x = (const float*)d_in[0];
  const float* Wf = (const float*)d_in[1];
  const float* bf = (const float*)d_in[2];
  const float* Wg = (const float*)d_in[3];
  const float* bg = (const float*)d_in[4];
  const float* Wh = (const float*)d_in[5];
  const float* bh = (const float*)d_in[6];
  const float* gamma = (const float*)d_in[7];
  float* out = (float*)d_out;

  char* ws = (char*)d_ws;
  // Layout (bytes):
  //   Q      [0,        1048576)
  //   K      [1048576,  2097152)
  //   Vt     [2097152, 10485760)
  //   M      [10485760, 10551296)
  //   lpart  [10551296, 10682368)   (<= 2 chunks)
  //   xT     [10682368, 19070976)   (dead after k_proj)
  //   Opart  [10682368, 10682368 + NC*8388608)  (overlays xT)
  _Float16* Q  = (_Float16*)(ws);
  _Float16* K  = (_Float16*)(ws + 1048576);
  _Float16* Vt = (_Float16*)(ws + 2097152);
  float*    M  = (float*)   (ws + 10485760);
  float*    lpart = (float*)(ws + 10551296);
  _Float16* xT = (_Float16*)(ws + 10682368);
  _Float16* Opart = (_Float16*)(ws + 10682368);

  size_t need2 = 10682368u + 2u * 8388608u;  // 27.5 MB for 2-way n-split
  int NC = (ws_size >= need2) ? 2 : 1;
  int nspan = Nn / NC;

  k_xt<<<dim3(1024), dim3(256), 0, stream>>>(x, xT);
  k_proj<<<dim3(1280), dim3(256), 0, stream>>>(xT, Wf, bf, Wg, bg, Wh, bh, Q, K, Vt);
  k_rowmax<<<dim3(512), dim3(512), 0, stream>>>(Q, K, M);
  k_attn<<<dim3(NC * 256), dim3(512), 0, stream>>>(Q, K, Vt, M, Opart, lpart, nspan);
  k_fin<<<dim3(4096), dim3(256), 0, stream>>>(Opart, lpart, x, gamma, out, NC);
}

// Round 4
// 193.864 us; speedup vs baseline: 1.3922x; 1.0243x over previous
//
#include <hip/hip_runtime.h>

typedef _Float16 half8 __attribute__((ext_vector_type(8)));
typedef _Float16 half4 __attribute__((ext_vector_type(4)));
typedef float floatx16 __attribute__((ext_vector_type(16)));

#define MFMA_F16(A, B, C) __builtin_amdgcn_mfma_f32_32x32x16_f16(A, B, C, 0, 0, 0)

constexpr int Bn = 4;     // batch
constexpr int Cc = 256;   // channels
constexpr int Cq = 32;    // C/8
constexpr int Nn = 4096;  // tokens (64*64)
constexpr float LOG2E = 1.44269504088896340736f;

__device__ inline floatx16 zero16() {
  floatx16 z;
#pragma unroll
  for (int i = 0; i < 16; ++i) z[i] = 0.f;
  return z;
}

// ---------------------------------------------------------------------------
// Kernel 0: blocks [0,1024): x[b][c][n] fp32 -> xT[b][n][c] f16 (LDS transpose)
//           blocks [1024,1104): W fp32 -> f16 (Wf scaled by log2e)
// ---------------------------------------------------------------------------
__global__ __launch_bounds__(256) void k_xt(
    const float* __restrict__ x, _Float16* __restrict__ xT,
    const float* __restrict__ Wf, const float* __restrict__ Wg,
    const float* __restrict__ Wh, _Float16* __restrict__ Wfh,
    _Float16* __restrict__ Wgh, _Float16* __restrict__ Whh) {
  int blk = blockIdx.x;
  if (blk >= 1024) {
    // ---- W convert tail: 80 blocks x 256 thr x 4 elems = 81920 fp32 ----
    int e = ((blk - 1024) * 256 + threadIdx.x) * 4;
    const float* src;
    _Float16* dst;
    float sc = 1.f;
    if (e < 8192) { src = Wf + e; dst = Wfh + e; sc = LOG2E; }
    else if (e < 16384) { src = Wg + (e - 8192); dst = Wgh + (e - 8192); }
    else { src = Wh + (e - 16384); dst = Whh + (e - 16384); }
    float4 v = *(const float4*)src;
    half4 o;
    o[0] = (_Float16)(v.x * sc); o[1] = (_Float16)(v.y * sc);
    o[2] = (_Float16)(v.z * sc); o[3] = (_Float16)(v.w * sc);
    *(half4*)dst = o;
    return;
  }
  __shared__ _Float16 t[64 * 66];
  int b = blk >> 8;
  int rem = blk & 255;
  int ct = rem & 3, nt = rem >> 2;
  int c0 = ct * 64, n0 = nt * 64;
  int tid = threadIdx.x;
  int col = tid & 63, row4 = tid >> 6;
  const float* xp = x + ((size_t)b * Cc + c0) * Nn + n0;
#pragma unroll
  for (int it = 0; it < 16; ++it) {
    int cl = it * 4 + row4;
    t[cl * 66 + col] = (_Float16)xp[(size_t)cl * Nn + col];
  }
  __syncthreads();
  _Float16* op = xT + ((size_t)b * Nn + n0) * Cc + c0;
#pragma unroll
  for (int it = 0; it < 16; ++it) {
    int nl = it * 4 + row4;
    op[(size_t)nl * Cc + col] = t[col * 66 + nl];
  }
}

// ---------------------------------------------------------------------------
// Kernel 1: projections, now reading pre-converted f16 weights (no cvt VALU).
// Q is scaled by log2e (via Wfh scale + bias scale) for the exp2 softmax.
// ---------------------------------------------------------------------------
__global__ __launch_bounds__(256) void k_proj(
    const _Float16* __restrict__ xT,
    const _Float16* __restrict__ Wfh, const float* __restrict__ bf,
    const _Float16* __restrict__ Wgh, const float* __restrict__ bg,
    const _Float16* __restrict__ Whh, const float* __restrict__ bh,
    _Float16* __restrict__ Q, _Float16* __restrict__ K,
    _Float16* __restrict__ Vt) {
  int tid = threadIdx.x;
  int wave = tid >> 6, lane = tid & 63;
  int ml = lane & 31, h = lane >> 5;
  int jid = blockIdx.x * 4 + wave;
  floatx16 acc = zero16();

  if (jid < 1024) {
    const _Float16* W = (jid < 512) ? Wfh : Wgh;
    const float* bias = (jid < 512) ? bf : bg;
    _Float16* dst = (jid < 512) ? Q : K;
    float bscale = (jid < 512) ? LOG2E : 1.f;
    int j2 = jid & 511;
    int b = j2 >> 7, nt = j2 & 127;
    int n0 = nt * 32;
    const _Float16* ap = xT + ((size_t)b * Nn + n0 + ml) * Cc + h * 8;
    const _Float16* wp = W + (size_t)ml * Cc + h * 8;
#pragma unroll
    for (int kc = 0; kc < 16; ++kc) {
      half8 a = *(const half8*)(ap + kc * 16);
      half8 wv = *(const half8*)(wp + kc * 16);
      acc = MFMA_F16(a, wv, acc);
    }
    float bv = bias[ml] * bscale;
    _Float16* op = dst + ((size_t)b * Nn + n0) * Cq + ml;
#pragma unroll
    for (int r = 0; r < 16; ++r) {
      int row = (r & 3) + 8 * (r >> 2) + 4 * h;
      op[(size_t)row * Cq] = (_Float16)(acc[r] + bv);
    }
  } else {
    int v = jid - 1024;
    int b = v >> 10, r2 = v & 1023;
    int ct = r2 >> 7, nt = r2 & 127;
    int c0 = ct * 32, n0 = nt * 32;
    const _Float16* wp = Whh + (size_t)(c0 + ml) * Cc + h * 8;
    const _Float16* bp = xT + ((size_t)b * Nn + n0 + ml) * Cc + h * 8;
#pragma unroll
    for (int kc = 0; kc < 16; ++kc) {
      half8 wv = *(const half8*)(wp + kc * 16);
      half8 bfrag = *(const half8*)(bp + kc * 16);
      acc = MFMA_F16(wv, bfrag, acc);
    }
    _Float16* op = Vt + ((size_t)b * Cc + c0) * (size_t)Nn + n0 + ml;
#pragma unroll
    for (int q = 0; q < 4; ++q) {
      float4 bq = *(const float4*)(bh + c0 + 8 * q + 4 * h);
      const float* bqp = (const float*)&bq;
#pragma unroll
      for (int i = 0; i < 4; ++i) {
        int row = 8 * q + 4 * h + i;
        op[(size_t)row * Nn] = (_Float16)(acc[4 * q + i] + bqp[i]);
      }
    }
  }
}

// ---------------------------------------------------------------------------
// Kernel 2: pass-1 row max (log2-domain since Q is pre-scaled).
// MFMA sequence bitwise identical to k_attn's S -> exp2(s-M) <= 1 exactly.
// ---------------------------------------------------------------------------
__global__ __launch_bounds__(512) void k_rowmax(const _Float16* __restrict__ Q,
                                                const _Float16* __restrict__ K,
                                                float* __restrict__ M) {
  __shared__ float red[8][32];
  int tid = threadIdx.x, w = tid >> 6, lane = tid & 63;
  int ml = lane & 31, h = lane >> 5;
  int b = blockIdx.x >> 7, mt = blockIdx.x & 127;
  int m0 = mt * 32;
  const _Float16* qp = Q + ((size_t)b * Nn + m0 + ml) * Cq + h * 8;
  half8 qb0 = *(const half8*)(qp);
  half8 qb1 = *(const half8*)(qp + 16);
  const _Float16* kp = K + ((size_t)b * Nn + w * 512 + ml) * Cq + h * 8;
  float mx = -3.0e38f;
  for (int t = 0; t < 16; ++t) {
    floatx16 s = zero16();
    half8 k0 = *(const half8*)(kp + (size_t)t * 32 * Cq);
    half8 k1 = *(const half8*)(kp + (size_t)t * 32 * Cq + 16);
    s = MFMA_F16(k0, qb0, s);
    s = MFMA_F16(k1, qb1, s);
#pragma unroll
    for (int i = 0; i < 16; ++i) mx = fmaxf(mx, s[i]);
  }
  mx = fmaxf(mx, __shfl_xor(mx, 32, 64));
  if (h == 0) red[w][ml] = mx;
  __syncthreads();
  if (tid < 32) {
    float m2 = red[0][tid];
#pragma unroll
    for (int i = 1; i < 8; ++i) m2 = fmaxf(m2, red[i][tid]);
    M[(size_t)b * Nn + m0 + tid] = m2;
  }
}

// ---------------------------------------------------------------------------
// Kernel 3: pass-2 attention v4 — SOFTWARE-PIPELINED.
// Loop body: [write P(t); barrier; S(t+1) MFMA+exp2  ||  PV(t) LDS+MFMA]
// so the exp VALU stream overlaps the PV MFMA/LDS stream between barriers.
// Single barrier/iter is safe: write(t+1) targets buf (t+1)&1 whose last
// readers (PV(t-1)) precede barrier(t) in every wave's program order.
// P layout: [2][64 m][128 n] stride 128, 16B-chunk XOR swizzle
// chunk' = chunk ^ (ml & 15): PV reads = conflict-free ds_read_b128.
// Last-iter S is computed at a clamped address and masked out of lacc.
// ---------------------------------------------------------------------------
__global__ __launch_bounds__(512, 4) void k_attn(
    const _Float16* __restrict__ Q, const _Float16* __restrict__ K,
    const _Float16* __restrict__ Vt, const float* __restrict__ M,
    _Float16* __restrict__ Opart, float* __restrict__ lpart, int nspan) {
  __shared__ _Float16 P[2 * 64 * 128];
  __shared__ float lred[8][32];
  int tid = threadIdx.x, w = tid >> 6, lane = tid & 63;
  int ml = lane & 31, h = lane >> 5;
  int msub = w & 1, nq = w >> 1;
  int bx = blockIdx.x;
  int mt = bx & 63, b = (bx >> 6) & 3, nc = bx >> 8;
  int m0 = mt * 64;
  int nbase0 = nc * nspan;
  int sw = ml & 15;

  const _Float16* qp = Q + ((size_t)b * Nn + m0 + msub * 32 + ml) * Cq + h * 8;
  half8 qb0 = *(const half8*)(qp);
  half8 qb1 = *(const half8*)(qp + 16);
  float Mv = M[(size_t)b * Nn + m0 + msub * 32 + ml];
  float lacc = 0.f;

  const _Float16* kbase =
      K + ((size_t)b * Nn + nbase0 + nq * 32 + ml) * Cq + h * 8;
  int c0 = w * 32;
  const _Float16* vbase =
      Vt + ((size_t)b * Cc + c0 + ml) * (size_t)Nn + nbase0 + h * 8;

  floatx16 o0 = zero16(), o1 = zero16();
  int iters = nspan >> 7;
  _Float16* pwbase = &P[(msub * 32 + ml) * 128];
  const _Float16* pr0 = &P[ml * 128];
  const _Float16* pr1 = &P[(32 + ml) * 128];

  half4 pk[4];
  // S-compute for a tile at n-offset noff; mask excludes dummy last tile.
  auto compS = [&](int noff, float mask) {
    floatx16 s = zero16();
    const _Float16* kp = kbase + (size_t)noff * Cq;
    half8 k0 = *(const half8*)(kp);
    half8 k1 = *(const half8*)(kp + 16);
    s = MFMA_F16(k0, qb0, s);
    s = MFMA_F16(k1, qb1, s);
#pragma unroll
    for (int q = 0; q < 4; ++q) {
      float p0 = exp2f(s[4 * q + 0] - Mv);
      float p1 = exp2f(s[4 * q + 1] - Mv);
      float p2 = exp2f(s[4 * q + 2] - Mv);
      float p3 = exp2f(s[4 * q + 3] - Mv);
      lacc += mask * ((p0 + p1) + (p2 + p3));
      pk[q][0] = (_Float16)p0; pk[q][1] = (_Float16)p1;
      pk[q][2] = (_Float16)p2; pk[q][3] = (_Float16)p3;
    }
  };

  compS(0, 1.f);  // prologue: S(0)

  for (int it = 0; it < iters; ++it) {
    // ---- write P(t) ----
    _Float16* pw = pwbase + (it & 1) * (64 * 128);
#pragma unroll
    for (int q = 0; q < 4; ++q)
      *(half4*)(pw + ((nq * 4 + q) ^ sw) * 8 + 4 * h) = pk[q];
    __syncthreads();
    // ---- S(t+1) (independent of PV(t): compiler may interleave) ----
    int lastf = (it + 1 == iters) ? 1 : 0;
    compS((it + 1 - lastf) * 128, lastf ? 0.f : 1.f);
    // ---- PV(t) ----
    const _Float16* vp = vbase + it * 128;
    const _Float16* p0b = pr0 + (it & 1) * (64 * 128);
    const _Float16* p1b = pr1 + (it & 1) * (64 * 128);
#pragma unroll
    for (int kc = 0; kc < 8; ++kc) {
      half8 vf = *(const half8*)(vp + kc * 16);
      int chunk = (kc * 2 + h) ^ sw;
      half8 pb0 = *(const half8*)(p0b + chunk * 8);  // ds_read_b128
      half8 pb1 = *(const half8*)(p1b + chunk * 8);
      o0 = MFMA_F16(vf, pb0, o0);
      o1 = MFMA_F16(vf, pb1, o1);
    }
  }

  // ---- l reduction ----
  lacc += __shfl_xor(lacc, 32, 64);
  if (h == 0) lred[w][ml] = lacc;
  __syncthreads();
  if (w < 2 && h == 0) {
    float lsum = lred[w][ml] + lred[w + 2][ml] + lred[w + 4][ml] + lred[w + 6][ml];
    lpart[((size_t)nc * Bn + b) * Nn + m0 + w * 32 + ml] = lsum;
  }

  // ---- store unnormalized O^T partials (f16) ----
  _Float16* op0 = Opart + ((size_t)((size_t)nc * Bn + b) * Cc) * Nn + (m0 + ml);
#pragma unroll
  for (int r = 0; r < 16; ++r) {
    int c = c0 + (r & 3) + 8 * (r >> 2) + 4 * h;
    op0[(size_t)c * Nn] = (_Float16)o0[r];
    op0[(size_t)c * Nn + 32] = (_Float16)o1[r];
  }
}

// ---------------------------------------------------------------------------
// Kernel 4: combine chunk partials: out = gamma*(sum O)/(sum l) + input
// ---------------------------------------------------------------------------
__global__ __launch_bounds__(256) void k_fin(const _Float16* __restrict__ Op,
                                             const float* __restrict__ lp,
                                             const float* __restrict__ inp,
                                             const float* __restrict__ gamma,
                                             float* __restrict__ out, int NC) {
  int i4 = (blockIdx.x * 256 + threadIdx.x) * 4;
  int m = i4 & (Nn - 1);
  int bc = i4 >> 12;        // b*256 + c
  int b = bc >> 8;
  float ax = 0.f, ay = 0.f, az = 0.f, aw = 0.f;
  float lx = 0.f, ly = 0.f, lz = 0.f, lw = 0.f;
  for (int nc = 0; nc < NC; ++nc) {
    half4 o = *(const half4*)(Op + ((size_t)nc * Bn * Cc + bc) * Nn + m);
    float4 lv = *(const float4*)(lp + ((size_t)nc * Bn + b) * Nn + m);
    ax += (float)o[0]; ay += (float)o[1]; az += (float)o[2]; aw += (float)o[3];
    lx += lv.x; ly += lv.y; lz += lv.z; lw += lv.w;
  }
  float g = gamma[0];
  float4 xi = *(const float4*)(inp + (size_t)i4);
  float4 r;
  r.x = g * ax / lx + xi.x;
  r.y = g * ay / ly + xi.y;
  r.z = g * az / lz + xi.z;
  r.w = g * aw / lw + xi.w;
  *(float4*)(out + (size_t)i4) = r;
}

// ---------------------------------------------------------------------------
extern "C" void kernel_launch(void* const* d_in, const int* in_sizes, int n_in,
                              void* d_out, int out_size, void* d_ws,
                              size_t ws_size, hipStream_t stream) {
  const float* x = (const float*)d_in[0];
  const float* Wf = (const float*)d_in[1];
  const float* bf = (const float*)d_in[2];
  const float* Wg = (const float*)d_in[3];
  const float* bg = (const float*)d_in[4];
  const float* Wh = (const float*)d_in[5];
  const float* bh = (const float*)d_in[6];
  const float* gamma = (const float*)d_in[7];
  float* out = (float*)d_out;

  char* ws = (char*)d_ws;
  // Layout (bytes):
  //   Q      [0,        1048576)
  //   K      [1048576,  2097152)
  //   Vt     [2097152, 10485760)
  //   M      [10485760, 10551296)
  //   Wfh    [10551296, 10567680)
  //   Wgh    [10567680, 10584064)
  //   Whh    [10584064, 10715136)
  //   lpart  [10715136, 10846208)   (2 chunks x 64 KB)
  //   xT     [10846208, 19234816)   (dead after k_proj)
  //   Opart  [10846208, 10846208 + NC*8388608)  (overlays xT)
  _Float16* Q  = (_Float16*)(ws);
  _Float16* K  = (_Float16*)(ws + 1048576);
  _Float16* Vt = (_Float16*)(ws + 2097152);
  float*    M  = (float*)   (ws + 10485760);
  _Float16* Wfh = (_Float16*)(ws + 10551296);
  _Float16* Wgh = (_Float16*)(ws + 10567680);
  _Float16* Whh = (_Float16*)(ws + 10584064);
  float*    lpart = (float*)(ws + 10715136);
  _Float16* xT = (_Float16*)(ws + 10846208);
  _Float16* Opart = (_Float16*)(ws + 10846208);

  size_t need2 = 10846208u + 2u * 8388608u;  // ~27.6 MB for 2-way n-split
  int NC = (ws_size >= need2) ? 2 : 1;
  int nspan = Nn / NC;

  k_xt<<<dim3(1104), dim3(256), 0, stream>>>(x, xT, Wf, Wg, Wh, Wfh, Wgh, Whh);
  k_proj<<<dim3(1280), dim3(256), 0, stream>>>(xT, Wfh, bf, Wgh, bg, Whh, bh, Q, K, Vt);
  k_rowmax<<<dim3(512), dim3(512), 0, stream>>>(Q, K, M);
  k_attn<<<dim3(NC * 256), dim3(512), 0, stream>>>(Q, K, Vt, M, Opart, lpart, nspan);
  k_fin<<<dim3(4096), dim3(256), 0, stream>>>(Opart, lpart, x, gamma, out, NC);
}